// Round 1
// baseline (72.751 us; speedup 1.0000x reference)
//
#include <hip/hip_runtime.h>
#include <math.h>

// Problem constants (from reference)
#define FH 64    // feature map H (axis indexed by x)
#define FW 64    // feature map W (axis indexed by y)
#define FC 256   // channels
#define PP 7     // pool output dim
#define NROI 256

// Exact replication of reference _bin_bounds integer math.
// lo = floor(lo_f*size); hi = ceil(hi_f*size); span = max(hi-lo,1)
// start_i = lo + floor(i*span/P); end_i = lo + ceil((i+1)*span/P)
// len = max(end-start,1); start clipped to [0,size-1]
__device__ __forceinline__ void bin_bounds(float lof, float hif, int idx, int size,
                                           int& start, int& len) {
    int lo = (int)floorf(lof * (float)size);
    int hi = (int)ceilf(hif * (float)size);
    int span = hi - lo;
    span = span > 1 ? span : 1;
    int s0 = lo + (idx * span) / PP;                   // nonneg -> floor div
    int e0 = lo + ((idx + 1) * span + (PP - 1)) / PP;  // ceil div (nonneg)
    int l = e0 - s0;
    len = l > 1 ? l : 1;
    int s = s0 < 0 ? 0 : s0;
    start = s > (size - 1) ? (size - 1) : s;
}

__global__ __launch_bounds__(256) void roi_pool_kernel(
        const float* __restrict__ feat,   // (FH, FW, FC)
        const float* __restrict__ rois,   // (NROI, 4): x1,y1,x2,y2
        float* __restrict__ out)          // (NROI, PP, PP, FC)
{
    int gtid = blockIdx.x * blockDim.x + threadIdx.x;
    int lane = gtid & 63;          // channel group: 4 channels per lane (float4)
    int cell = gtid >> 6;          // (r, i, j) output cell
    if (cell >= NROI * PP * PP) return;

    int j = cell % PP;
    int t = cell / PP;
    int i = t % PP;
    int r = t / PP;

    float x1 = rois[r * 4 + 0];
    float y1 = rois[r * 4 + 1];
    float x2 = rois[r * 4 + 2];
    float y2 = rois[r * 4 + 3];

    int xs, xlen, ys, ylen;
    bin_bounds(x1, x2, i, FH, xs, xlen);   // along H (axis 0)
    bin_bounds(y1, y2, j, FW, ys, ylen);   // along W (axis 1)

    const float4* f4 = (const float4*)feat;   // (FH, FW, FC/4)
    float4 acc = make_float4(-INFINITY, -INFINITY, -INFINITY, -INFINITY);

    for (int sx = 0; sx < xlen; ++sx) {
        int x = xs + sx;
        x = x > (FH - 1) ? (FH - 1) : x;
        const float4* row = f4 + (size_t)(x * FW) * (FC / 4);
        for (int sy = 0; sy < ylen; ++sy) {
            int y = ys + sy;
            y = y > (FW - 1) ? (FW - 1) : y;
            float4 v = row[y * (FC / 4) + lane];
            acc.x = fmaxf(acc.x, v.x);
            acc.y = fmaxf(acc.y, v.y);
            acc.z = fmaxf(acc.z, v.z);
            acc.w = fmaxf(acc.w, v.w);
        }
    }

    ((float4*)out)[(size_t)cell * 64 + lane] = acc;
}

extern "C" void kernel_launch(void* const* d_in, const int* in_sizes, int n_in,
                              void* d_out, int out_size, void* d_ws, size_t ws_size,
                              hipStream_t stream) {
    const float* feat = (const float*)d_in[0];   // (1,64,64,256)
    const float* rois = (const float*)d_in[1];   // (1,256,4)
    float* out = (float*)d_out;                  // (1,256,7,7,256)

    const int total_threads = NROI * PP * PP * 64;  // one 64-lane wave per cell
    const int block = 256;
    const int grid = (total_threads + block - 1) / block;  // 3136
    roi_pool_kernel<<<grid, block, 0, stream>>>(feat, rois, out);
}